// Round 16
// baseline (405.015 us; speedup 1.0000x reference)
//
#include <hip/hip_runtime.h>
#include <math.h>

#define Bb    32
#define Nn    4096
#define HISTC 16
#define PREDC 8
#define TTC   24
#define EC    65536
#define BN    (Bb*Nn)          // 131072
#define NSL   768              // 512 hist + 256 pred slices

typedef float f32x2 __attribute__((ext_vector_type(2)));
typedef float f32x4 __attribute__((ext_vector_type(4)));
typedef __fp16 f16x8 __attribute__((ext_vector_type(8)));
typedef __fp16 fp16v2 __attribute__((ext_vector_type(2)));

__device__ __forceinline__ float sigm_f(float x){
  return __builtin_amdgcn_rcpf(1.f + __expf(-x));
}
__device__ __forceinline__ unsigned pk2(float a, float b){
  fp16v2 v = __builtin_amdgcn_cvt_pkrtz(a, b);
  return __builtin_bit_cast(unsigned, v);
}
__device__ __forceinline__ void unpk2(unsigned u, float& a, float& b){
  fp16v2 v = __builtin_bit_cast(fp16v2, u);
  a = (float)v.x; b = (float)v.y;
}
__device__ __forceinline__ f32x4 mfma16(uint4 a, uint4 b, f32x4 c){
  return __builtin_amdgcn_mfma_f32_16x16x32_f16(
      __builtin_bit_cast(f16x8, a), __builtin_bit_cast(f16x8, b), c, 0, 0, 0);
}

// ---------------- CSR build ----------------
__global__ void k_deg(const int* __restrict__ ei, int* deg, int* cnt){
  int e = blockIdx.x*blockDim.x + threadIdx.x;
  if (e < EC){ atomicAdd(&deg[ei[e]],1); atomicAdd(&cnt[ei[EC+e]],1); }
}
__global__ void k_scan(const int* __restrict__ cnt, int* ptr){
  __shared__ int sd[1024];
  int t = threadIdx.x;
  int c0=cnt[4*t], c1=cnt[4*t+1], c2=cnt[4*t+2], c3=cnt[4*t+3];
  int s = c0+c1+c2+c3;
  sd[t] = s; __syncthreads();
  for (int off=1; off<1024; off<<=1){
    int v = (t>=off) ? sd[t-off] : 0;
    __syncthreads();
    sd[t] += v;
    __syncthreads();
  }
  int excl = sd[t]-s;
  ptr[4*t]=excl; ptr[4*t+1]=excl+c0; ptr[4*t+2]=excl+c0+c1; ptr[4*t+3]=excl+c0+c1+c2;
  if (t==1023) ptr[4096]=sd[1023];
}
// merged: block 0 -> dis; blocks 1..8 -> weight-fragment build
__global__ void k_misc(const int* __restrict__ deg, float* __restrict__ dis,
                       const float* __restrict__ x2hw, const float* __restrict__ h2hw,
                       const float* __restrict__ x2hb, const float* __restrict__ h2hb,
                       _Float16* __restrict__ wfrag){
  if (blockIdx.x == 0){
    #pragma unroll
    for (int k=0;k<4;++k){
      int n = threadIdx.x + k*1024;
      dis[n] = deg[n] > 0 ? rsqrtf((float)deg[n]) : 0.f;
    }
  } else {
    int i = (blockIdx.x-1)*1024 + threadIdx.x;     // 8192 total
    int f = i >> 9, lane = (i >> 3) & 63, j = i & 7;
    int kt = f >> 3, ct = f & 7;
    int k = kt*32 + (lane>>4)*8 + j;
    int col = ct*16 + (lane&15);
    float v;
    if (k < 12)       v = x2hw[k*128 + col];
    else if (k == 12) v = x2hb[col] + h2hb[col];
    else if (k < 32)  v = 0.f;
    else              v = h2hw[(k-32)*128 + col];
    wfrag[f*512 + lane*8 + j] = (_Float16)v;
  }
}
__global__ void k_fill(const int* __restrict__ ei, const float* __restrict__ dis,
                       const int* __restrict__ ptr, int* fillc, int2* __restrict__ epack){
  int e = blockIdx.x*blockDim.x + threadIdx.x;
  if (e < EC){
    int s = ei[e], d = ei[EC+e];
    int pos = ptr[d] + atomicAdd(&fillc[d],1);
    epack[pos] = make_int2(s, __float_as_int(-dis[s]*dis[d]));
  }
}

// ---------------- all z slices: hist [0,512) + pred feat-z [512,768) ----------
__global__ __launch_bounds__(256)
void k_zall(const float* __restrict__ pm25, const float* __restrict__ feat,
            const float* __restrict__ cw, f32x2* __restrict__ zAll){
  int r = blockIdx.x*256 + threadIdx.x;     // ts*BN + bn, ts in [0,24)
  int ts = r >> 17, bn = r & (BN-1);
  int b = bn >> 12, n = bn & (Nn-1);
  const float* fp = feat + ((size_t)(b*TTC + ts)*Nn + n)*9;
  float z0=0.f, z1=0.f;
  int slice;
  if (ts < HISTC){
    float x0 = pm25[(size_t)(b*HISTC + ts)*Nn + n];
    z0 = x0*cw[20]; z1 = x0*cw[21];
    #pragma unroll
    for (int f=0;f<9;++f){
      float v = fp[f];
      z0 = fmaf(v, cw[20+(f+1)*2+0], z0); z1 = fmaf(v, cw[20+(f+1)*2+1], z1);
    }
    slice = ts*Bb + b;
  } else {
    #pragma unroll
    for (int f=0;f<9;++f){
      float v = fp[f];
      z0 = fmaf(v, cw[20+(f+1)*2+0], z0); z1 = fmaf(v, cw[20+(f+1)*2+1], z1);
    }
    slice = 512 + (ts-HISTC)*Bb + b;
  }
  zAll[(size_t)slice*Nn + n] = (f32x2){z0, z1};
}

// ---------------- generic tiled transpose of f32x2 matrix [R][C] -> [C][R] ----
__global__ __launch_bounds__(256)
void k_tr(const f32x2* __restrict__ in, f32x2* __restrict__ out, int R, int C){
  __shared__ f32x2 tile[64][65];
  int tilesR = R >> 6;
  int br = blockIdx.x % tilesR, bc = blockIdx.x / tilesR;
  int r0 = br << 6, c0 = bc << 6;
  for (int i=threadIdx.x; i<4096; i+=256){
    int r = i>>6, c = i&63;
    tile[r][c] = in[(size_t)(r0+r)*C + c0+c];
  }
  __syncthreads();
  for (int i=threadIdx.x; i<4096; i+=256){
    int r = i>>6, c = i&63;
    out[(size_t)(c0+r)*R + r0+c] = tile[c][r];
  }
}

// ---------------- column-split dense agg: 6 passes of 64 float4 cols ----------
__global__ __launch_bounds__(64)
void k_aggc(const int* __restrict__ ptr, const int2* __restrict__ epack,
            const float4* __restrict__ zT, float4* __restrict__ aggT){
  int n  = blockIdx.x & (Nn-1);
  int cb = blockIdx.x >> 12;
  int col = cb*64 + threadIdx.x;              // float4 index in 384-wide row
  int p0 = ptr[n], p1 = ptr[n+1];
  f32x4 acc = {0.f,0.f,0.f,0.f};
  int i = p0;
  for (; i+1 < p1; i += 2){
    int2 e0 = epack[i], e1 = epack[i+1];
    float w0 = __int_as_float(e0.y), w1 = __int_as_float(e1.y);
    float4 z0 = zT[(size_t)e0.x*384 + col];
    float4 z1 = zT[(size_t)e1.x*384 + col];
    acc.x = fmaf(w0, z0.x, acc.x); acc.y = fmaf(w0, z0.y, acc.y);
    acc.z = fmaf(w0, z0.z, acc.z); acc.w = fmaf(w0, z0.w, acc.w);
    acc.x = fmaf(w1, z1.x, acc.x); acc.y = fmaf(w1, z1.y, acc.y);
    acc.z = fmaf(w1, z1.z, acc.z); acc.w = fmaf(w1, z1.w, acc.w);
  }
  if (i < p1){
    int2 e = epack[i];
    float w = __int_as_float(e.y);
    float4 z = zT[(size_t)e.x*384 + col];
    acc.x = fmaf(w, z.x, acc.x); acc.y = fmaf(w, z.y, acc.y);
    acc.z = fmaf(w, z.z, acc.z); acc.w = fmaf(w, z.w, acc.w);
  }
  aggT[(size_t)n*384 + col] = make_float4(acc.x, acc.y, acc.z, acc.w);
}

// ---------------- per-step sparse matvec: aggx[b][n] = sum_e w_e*xnT[src][b] --
__global__ __launch_bounds__(256)
void k_aggx(const int* __restrict__ ptr, const int2* __restrict__ epack,
            const float* __restrict__ xnT, float* __restrict__ aggx){
  int lane = threadIdx.x & 63, w = threadIdx.x >> 6;
  int n = blockIdx.x*4 + w;
  int b = lane & 31, half = lane >> 5;
  int p0 = ptr[n], p1 = ptr[n+1];
  float acc = 0.f;
  for (int i = p0 + half; i < p1; i += 2){
    int2 e = epack[i];
    acc = fmaf(__int_as_float(e.y), xnT[(size_t)e.x*32 + b], acc);
  }
  acc += __shfl_xor(acc, 32);
  if (lane < 32) aggx[(size_t)b*Nn + n] = acc;
}

// ---------------- shared-rcp LSTM pointwise: 7 trans/unit (was 10) -----------
// c' = [c*di*dg + (Eg-1)*df] / (di*df*dg);  h' = (Ec-1)/((Ec+1)(1+Eo))
#define PW(r)                                                                     \
  {                                                                               \
    float Ei0=__expf(fmaxf(-acc[0][r],-30.f)), Ef0=__expf(fmaxf(-acc[2][r],-30.f));\
    float Eg0=__expf(fminf(2.f*acc[4][r],60.f)), Eo0=__expf(fmaxf(-acc[6][r],-30.f));\
    float di0=1.f+Ei0, df0=1.f+Ef0, dg0=1.f+Eg0;                                  \
    float nu0=fmaf(c0[r]*di0, dg0, (Eg0-1.f)*df0);                                \
    c0[r]=nu0*__builtin_amdgcn_rcpf(di0*df0*dg0);                                 \
    float Ec0=__expf(2.f*c0[r]);                                                  \
    h0[r]=(Ec0-1.f)*__builtin_amdgcn_rcpf((Ec0+1.f)*(1.f+Eo0));                   \
    float Ei1=__expf(fmaxf(-acc[1][r],-30.f)), Ef1=__expf(fmaxf(-acc[3][r],-30.f));\
    float Eg1=__expf(fminf(2.f*acc[5][r],60.f)), Eo1=__expf(fmaxf(-acc[7][r],-30.f));\
    float di1=1.f+Ei1, df1=1.f+Ef1, dg1=1.f+Eg1;                                  \
    float nu1=fmaf(c1[r]*di1, dg1, (Eg1-1.f)*df1);                                \
    c1[r]=nu1*__builtin_amdgcn_rcpf(di1*df1*dg1);                                 \
    float Ec1=__expf(2.f*c1[r]);                                                  \
    h1[r]=(Ec1-1.f)*__builtin_amdgcn_rcpf((Ec1+1.f)*(1.f+Eo1));                   \
  }

// ---------------- persistent history LSTM: weights in LDS, 1 tile/wave --------
__global__ __launch_bounds__(256,1)
void k_hist(const float* __restrict__ pm25, const float* __restrict__ feat,
            const f32x2* __restrict__ aggH,
            const float* __restrict__ cw, const float* __restrict__ cb,
            const uint4* __restrict__ wfrag,
            const float* __restrict__ fcw, const float* __restrict__ fcb,
            uint4* __restrict__ hfragO, uint4* __restrict__ cO,
            float* __restrict__ xn0, float* __restrict__ xnT){
  __shared__ __align__(16) uint4 wl[1024];          // 16 KB weight fragments
  __shared__ __align__(16) _Float16 hl[4][16][40];
  int tid = threadIdx.x;
  int lane = tid & 63, w = tid >> 6;
  for (int i = tid; i < 1024; i += 256) wl[i] = wfrag[i];
  int gw = blockIdx.x*4 + w;
  int r0 = gw*16;
  int b = r0 >> 12, n0 = r0 & (Nn-1);
  int l15 = lane & 15, g4 = lane >> 4;
  int nrow = n0 + l15;
  const float* pb = pm25 + (size_t)b*HISTC*Nn + nrow;
  const float* fb = feat + ((size_t)b*TTC*Nn + nrow)*9;

  float fw0 = fcw[l15], fw1 = fcw[l15+16];
  const f32x4 zacc = {0.f,0.f,0.f,0.f};

  uint4 ah = make_uint4(0,0,0,0);
  float c0[4]={0,0,0,0}, c1[4]={0,0,0,0};
  float h0[4], h1[4];
  __syncthreads();                                  // wl ready

  #pragma unroll 1
  for (int t=0; t<HISTC; ++t){
    int wofs = lane;
    asm volatile("" : "+v"(wofs));                  // opaque: prevent hoisting wl reads
    const float* fbt = fb + (size_t)t*Nn*9;
    float xv[9]; float a0 = 0.f, a1 = 0.f; float x0 = 0.f;
    if (g4 == 0){
      x0 = pb[(size_t)t*Nn];
      #pragma unroll
      for (int f=0;f<7;++f) xv[f] = fbt[f];
      a0 = x0*cw[0]; a1 = x0*cw[1];
      #pragma unroll
      for (int f=0;f<7;++f){ a0 += xv[f]*cw[(f+1)*2]; a1 += xv[f]*cw[(f+1)*2+1]; }
    } else if (g4 == 1){
      xv[7] = fbt[7]; xv[8] = fbt[8];
      a0 = cb[0] + xv[7]*cw[16] + xv[8]*cw[18];
      a1 = cb[1] + xv[7]*cw[17] + xv[8]*cw[19];
    } else if (g4 == 2){
      f32x2 ag = aggH[((size_t)(t*Bb + b))*Nn + nrow];
      a0 = ag.x; a1 = ag.y;
    }
    a0 += __shfl_xor(a0, 16); a0 += __shfl_xor(a0, 32);
    a1 += __shfl_xor(a1, 16); a1 += __shfl_xor(a1, 32);
    float xg0 = sigm_f(a0), xg1 = sigm_f(a1);

    uint4 ax;
    if (g4 == 0){
      ax.x = pk2(x0, xv[0]);     ax.y = pk2(xv[1], xv[2]);
      ax.z = pk2(xv[3], xv[4]);  ax.w = pk2(xv[5], xv[6]);
    } else if (g4 == 1){
      ax.x = pk2(xv[7], xv[8]);  ax.y = pk2(xg0, xg1);
      ax.z = pk2(1.f, 0.f);      ax.w = 0u;
    } else {
      ax = make_uint4(0,0,0,0);
    }

    f32x4 acc[8];
    #pragma unroll
    for (int ct=0; ct<8; ++ct){
      uint4 b0 = wl[wofs + ct*64];
      uint4 b1 = wl[wofs + 512 + ct*64];
      acc[ct] = mfma16(ax, b0, zacc);
      acc[ct] = mfma16(ah, b1, acc[ct]);
    }

    PW(0) PW(1) PW(2) PW(3)

    #pragma unroll
    for (int r=0;r<4;++r){
      hl[w][g4*4+r][l15]    = (_Float16)h0[r];
      hl[w][g4*4+r][l15+16] = (_Float16)h1[r];
    }
    asm volatile("s_waitcnt lgkmcnt(0)" ::: "memory");
    ah = *(const uint4*)&hl[w][l15][g4*8];
  }

  hfragO[(size_t)gw*64 + lane] = ah;
  {
    uint4 cp;
    cp.x = pk2(c0[0], c0[1]); cp.y = pk2(c0[2], c0[3]);
    cp.z = pk2(c1[0], c1[1]); cp.w = pk2(c1[2], c1[3]);
    cO[(size_t)gw*64 + lane] = cp;
  }
  #pragma unroll
  for (int r=0;r<4;++r){
    float p = fmaf(h0[r], fw0, h1[r]*fw1);
    p += __shfl_xor(p, 1, 16); p += __shfl_xor(p, 2, 16);
    p += __shfl_xor(p, 4, 16); p += __shfl_xor(p, 8, 16);
    if (l15 == 0){
      float rr = p + fcb[0];
      int nr = n0 + g4*4 + r;
      xn0[r0 + g4*4 + r] = rr;
      xnT[(size_t)nr*32 + b] = rr;
    }
  }
}

// ---------------- pred step: weights in LDS + dense agg reads + MFMA cell -----
__global__ __launch_bounds__(256,1)
void k_pred_cell(const float* __restrict__ feat, float* __restrict__ xn0,
                 const f32x2* __restrict__ aggzf,     // pre-offset by (512+tp*32)*Nn
                 const float* __restrict__ aggx,
                 const float* __restrict__ cw, const float* __restrict__ cb,
                 const uint4* __restrict__ wfrag,
                 const float* __restrict__ fcw, const float* __restrict__ fcb,
                 uint4* __restrict__ hfrag, uint4* __restrict__ cS,
                 float* __restrict__ xnT, float* __restrict__ out, int t){
  __shared__ __align__(16) uint4 wl[1024];
  __shared__ __align__(16) _Float16 hl[4][16][40];
  int tid = threadIdx.x;
  int lane = tid & 63, w = tid >> 6;
  for (int i = tid; i < 1024; i += 256) wl[i] = wfrag[i];
  int gw = blockIdx.x*4 + w;
  int r0 = gw*16;
  int b = r0 >> 12, n0 = r0 & (Nn-1);
  int l15 = lane & 15, g4 = lane >> 4;
  int nrow = n0 + l15;

  float fw0 = fcw[l15], fw1 = fcw[l15+16];

  uint4 ah = hfrag[(size_t)gw*64 + lane];
  float c0[4], c1[4];
  {
    uint4 cv = cS[(size_t)gw*64 + lane];
    unpk2(cv.x, c0[0], c0[1]); unpk2(cv.y, c0[2], c0[3]);
    unpk2(cv.z, c1[0], c1[1]); unpk2(cv.w, c1[2], c1[3]);
  }
  float h0[4], h1[4];
  const f32x4 zacc = {0.f,0.f,0.f,0.f};

  const float* fbt = feat + ((size_t)(b*TTC + t)*Nn + nrow)*9;
  float xv[9]; float a0 = 0.f, a1 = 0.f; float x0 = 0.f;
  if (g4 == 0){
    x0 = xn0[r0 + l15];
    #pragma unroll
    for (int f=0;f<7;++f) xv[f] = fbt[f];
    a0 = x0*cw[0]; a1 = x0*cw[1];
    #pragma unroll
    for (int f=0;f<7;++f){ a0 += xv[f]*cw[(f+1)*2]; a1 += xv[f]*cw[(f+1)*2+1]; }
  } else if (g4 == 1){
    xv[7] = fbt[7]; xv[8] = fbt[8];
    a0 = cb[0] + xv[7]*cw[16] + xv[8]*cw[18];
    a1 = cb[1] + xv[7]*cw[17] + xv[8]*cw[19];
  } else if (g4 == 2){
    f32x2 azf = aggzf[(size_t)b*Nn + nrow];
    float axv = aggx[(size_t)b*Nn + nrow];
    a0 = fmaf(cw[20], axv, azf.x);
    a1 = fmaf(cw[21], axv, azf.y);
  }
  a0 += __shfl_xor(a0, 16); a0 += __shfl_xor(a0, 32);
  a1 += __shfl_xor(a1, 16); a1 += __shfl_xor(a1, 32);
  float xg0 = sigm_f(a0), xg1 = sigm_f(a1);

  uint4 ax;
  if (g4 == 0){
    ax.x = pk2(x0, xv[0]);     ax.y = pk2(xv[1], xv[2]);
    ax.z = pk2(xv[3], xv[4]);  ax.w = pk2(xv[5], xv[6]);
  } else if (g4 == 1){
    ax.x = pk2(xv[7], xv[8]);  ax.y = pk2(xg0, xg1);
    ax.z = pk2(1.f, 0.f);      ax.w = 0u;
  } else {
    ax = make_uint4(0,0,0,0);
  }

  __syncthreads();                                  // wl ready
  f32x4 acc[8];
  #pragma unroll
  for (int ct=0; ct<8; ++ct){
    uint4 b0 = wl[lane + ct*64];
    uint4 b1 = wl[lane + 512 + ct*64];
    acc[ct] = mfma16(ax, b0, zacc);
    acc[ct] = mfma16(ah, b1, acc[ct]);
  }

  PW(0) PW(1) PW(2) PW(3)

  #pragma unroll
  for (int r=0;r<4;++r){
    hl[w][g4*4+r][l15]    = (_Float16)h0[r];
    hl[w][g4*4+r][l15+16] = (_Float16)h1[r];
  }
  asm volatile("s_waitcnt lgkmcnt(0)" ::: "memory");
  ah = *(const uint4*)&hl[w][l15][g4*8];

  hfrag[(size_t)gw*64 + lane] = ah;
  {
    uint4 cp;
    cp.x = pk2(c0[0], c0[1]); cp.y = pk2(c0[2], c0[3]);
    cp.z = pk2(c1[0], c1[1]); cp.w = pk2(c1[2], c1[3]);
    cS[(size_t)gw*64 + lane] = cp;
  }
  #pragma unroll
  for (int r=0;r<4;++r){
    float p = fmaf(h0[r], fw0, h1[r]*fw1);
    p += __shfl_xor(p, 1, 16); p += __shfl_xor(p, 2, 16);
    p += __shfl_xor(p, 4, 16); p += __shfl_xor(p, 8, 16);
    if (l15 == 0){
      float rr = p + fcb[0];
      int nr = n0 + g4*4 + r;
      xn0[r0 + g4*4 + r] = rr;
      xnT[(size_t)nr*32 + b] = rr;
      out[(size_t)b*PREDC*Nn + nr] = rr;      // out pre-offset by tp*Nn
    }
  }
}

// ---------------- host ----------------
extern "C" void kernel_launch(void* const* d_in, const int* in_sizes, int n_in,
                              void* d_out, int out_size, void* d_ws, size_t ws_size,
                              hipStream_t stream){
  const float* pm25 = (const float*)d_in[0];
  const float* feat = (const float*)d_in[1];
  const int*   ei   = (const int*)d_in[2];
  const float* cw   = (const float*)d_in[3];
  const float* cb   = (const float*)d_in[4];
  const float* x2hw = (const float*)d_in[5];
  const float* x2hb = (const float*)d_in[6];
  const float* h2hw = (const float*)d_in[7];
  const float* h2hb = (const float*)d_in[8];
  const float* fcw  = (const float*)d_in[9];
  const float* fcb  = (const float*)d_in[10];
  float* out = (float*)d_out;

  char* wsp = (char*)d_ws;
  size_t off = 0;
  auto take = [&](size_t bytes)->char*{
    char* r = wsp + off; off += (bytes + 255) & ~(size_t)255; return r;
  };
  int*      deg   = (int*)      take(Nn*4);
  int*      cnt   = (int*)      take(Nn*4);
  int*      fillc = (int*)      take(Nn*4);
  int*      ptr   = (int*)      take((Nn+1)*4);
  float*    dis   = (float*)    take(Nn*4);
  int2*     epack = (int2*)     take(EC*8);
  _Float16* wfrag = (_Float16*) take(16*512*2);
  char*     bufA  =             take((size_t)NSL*Nn*8);   // zAll -> aggT -> {hfrag,cbuf}
  char*     bufB  =             take((size_t)NSL*Nn*8);   // zT   -> aggAll
  float*    xn0   = (float*)    take((size_t)BN*4);
  float*    xnT   = (float*)    take((size_t)BN*4);       // [n][b]
  float*    aggx  = (float*)    take((size_t)BN*4);       // [b][n]

  f32x2* zAll = (f32x2*)bufA;
  f32x2* zT   = (f32x2*)bufB;
  uint4*  hfrag = (uint4*)bufA;                           // reuse after agg pipeline
  uint4*  cbuf  = (uint4*)(bufA + (size_t)8388608);       // f16-packed c state

  (void)hipMemsetAsync(deg, 0, Nn*4*3, stream);   // deg,cnt,fillc adjacent

  k_deg <<<EC/256, 256, 0, stream>>>(ei, deg, cnt);
  k_scan<<<1, 1024, 0, stream>>>(cnt, ptr);
  k_misc<<<9, 1024, 0, stream>>>(deg, dis, x2hw, h2hw, x2hb, h2hb, wfrag);
  k_fill<<<EC/256, 256, 0, stream>>>(ei, dis, ptr, fillc, epack);

  // dense agg pipeline over 768 combined slices (512 hist z + 256 pred zf)
  k_zall<<<(TTC*BN)/256, 256, 0, stream>>>(pm25, feat, cw, zAll);
  k_tr<<<(NSL/64)*(Nn/64), 256, 0, stream>>>(zAll, zT, NSL, Nn);     // zT[n][768]
  k_aggc<<<6*Nn, 64, 0, stream>>>(ptr, epack, (const float4*)zT, (float4*)zAll);
  k_tr<<<(Nn/64)*(NSL/64), 256, 0, stream>>>((const f32x2*)zAll, (f32x2*)bufB, Nn, NSL);

  const f32x2* aggAll = (const f32x2*)bufB;     // [768][4096]

  k_hist<<<BN/64, 256, 0, stream>>>(pm25, feat, aggAll, cw, cb,
                                    (const uint4*)wfrag, fcw, fcb,
                                    hfrag, cbuf, xn0, xnT);

  for (int tp = 0; tp < PREDC; ++tp){
    int t = HISTC + tp;
    k_aggx<<<Nn/4, 256, 0, stream>>>(ptr, epack, xnT, aggx);
    k_pred_cell<<<BN/64, 256, 0, stream>>>(feat, xn0,
                                           aggAll + (size_t)(512 + tp*Bb)*Nn, aggx,
                                           cw, cb, (const uint4*)wfrag, fcw, fcb,
                                           hfrag, cbuf, xnT, out + (size_t)tp*Nn, t);
  }
}

// Round 17
// 373.570 us; speedup vs baseline: 1.0842x; 1.0842x over previous
//
#include <hip/hip_runtime.h>
#include <math.h>

#define Bb    32
#define Nn    4096
#define HISTC 16
#define PREDC 8
#define TTC   24
#define EC    65536
#define BN    (Bb*Nn)          // 131072
#define NSL   768              // 512 hist + 256 pred slices

typedef float f32x2 __attribute__((ext_vector_type(2)));
typedef float f32x4 __attribute__((ext_vector_type(4)));
typedef __fp16 f16x8 __attribute__((ext_vector_type(8)));
typedef __fp16 fp16v2 __attribute__((ext_vector_type(2)));

__device__ __forceinline__ float sigm_f(float x){
  return __builtin_amdgcn_rcpf(1.f + __expf(-x));
}
__device__ __forceinline__ float tanh_f(float x){
  return fmaf(-2.f, __builtin_amdgcn_rcpf(1.f + __expf(2.f*x)), 1.f);
}
__device__ __forceinline__ unsigned pk2(float a, float b){
  fp16v2 v = __builtin_amdgcn_cvt_pkrtz(a, b);
  return __builtin_bit_cast(unsigned, v);
}
__device__ __forceinline__ void unpk2(unsigned u, float& a, float& b){
  fp16v2 v = __builtin_bit_cast(fp16v2, u);
  a = (float)v.x; b = (float)v.y;
}
__device__ __forceinline__ f32x4 mfma16(uint4 a, uint4 b, f32x4 c){
  return __builtin_amdgcn_mfma_f32_16x16x32_f16(
      __builtin_bit_cast(f16x8, a), __builtin_bit_cast(f16x8, b), c, 0, 0, 0);
}

// ---------------- CSR build ----------------
__global__ void k_deg(const int* __restrict__ ei, int* deg, int* cnt){
  int e = blockIdx.x*blockDim.x + threadIdx.x;
  if (e < EC){ atomicAdd(&deg[ei[e]],1); atomicAdd(&cnt[ei[EC+e]],1); }
}
__global__ void k_scan(const int* __restrict__ cnt, int* ptr){
  __shared__ int sd[1024];
  int t = threadIdx.x;
  int c0=cnt[4*t], c1=cnt[4*t+1], c2=cnt[4*t+2], c3=cnt[4*t+3];
  int s = c0+c1+c2+c3;
  sd[t] = s; __syncthreads();
  for (int off=1; off<1024; off<<=1){
    int v = (t>=off) ? sd[t-off] : 0;
    __syncthreads();
    sd[t] += v;
    __syncthreads();
  }
  int excl = sd[t]-s;
  ptr[4*t]=excl; ptr[4*t+1]=excl+c0; ptr[4*t+2]=excl+c0+c1; ptr[4*t+3]=excl+c0+c1+c2;
  if (t==1023) ptr[4096]=sd[1023];
}
// merged: block 0 -> dis; blocks 1..8 -> weight-fragment build
__global__ void k_misc(const int* __restrict__ deg, float* __restrict__ dis,
                       const float* __restrict__ x2hw, const float* __restrict__ h2hw,
                       const float* __restrict__ x2hb, const float* __restrict__ h2hb,
                       _Float16* __restrict__ wfrag){
  if (blockIdx.x == 0){
    #pragma unroll
    for (int k=0;k<4;++k){
      int n = threadIdx.x + k*1024;
      dis[n] = deg[n] > 0 ? rsqrtf((float)deg[n]) : 0.f;
    }
  } else {
    int i = (blockIdx.x-1)*1024 + threadIdx.x;     // 8192 total
    int f = i >> 9, lane = (i >> 3) & 63, j = i & 7;
    int kt = f >> 3, ct = f & 7;
    int k = kt*32 + (lane>>4)*8 + j;
    int col = ct*16 + (lane&15);
    float v;
    if (k < 12)       v = x2hw[k*128 + col];
    else if (k == 12) v = x2hb[col] + h2hb[col];
    else if (k < 32)  v = 0.f;
    else              v = h2hw[(k-32)*128 + col];
    wfrag[f*512 + lane*8 + j] = (_Float16)v;
  }
}
__global__ void k_fill(const int* __restrict__ ei, const float* __restrict__ dis,
                       const int* __restrict__ ptr, int* fillc, int2* __restrict__ epack){
  int e = blockIdx.x*blockDim.x + threadIdx.x;
  if (e < EC){
    int s = ei[e], d = ei[EC+e];
    int pos = ptr[d] + atomicAdd(&fillc[d],1);
    epack[pos] = make_int2(s, __float_as_int(-dis[s]*dis[d]));
  }
}

// ---------------- fused z + transpose: writes zT[n][slice] directly ----------
// block = 64 slices x 64 nodes tile; 768 blocks
__global__ __launch_bounds__(256)
void k_zt(const float* __restrict__ pm25, const float* __restrict__ feat,
          const float* __restrict__ cw, f32x2* __restrict__ zT){
  __shared__ f32x2 tile[64][65];
  int nb = blockIdx.x & 63, sb = blockIdx.x >> 6;   // sb 0..11
  int n0 = nb*64, s0 = sb*64;
  int tid = threadIdx.x;
  #pragma unroll
  for (int k=0;k<16;++k){
    int i = tid + k*256;
    int r = i >> 6, c = i & 63;                     // r = slice off, c = node off
    int slice = s0 + r, n = n0 + c;
    int b = slice & 31;
    int t;
    float z0, z1;
    if (slice < 512){
      t = (slice >> 5) & 15;
      float x0 = pm25[((size_t)(b*HISTC + t))*Nn + n];
      z0 = x0*cw[20]; z1 = x0*cw[21];
    } else {
      t = HISTC + ((slice - 512) >> 5);
      z0 = 0.f; z1 = 0.f;
    }
    const float* fp = feat + ((size_t)(b*TTC + t)*Nn + n)*9;
    #pragma unroll
    for (int f=0;f<9;++f){
      float v = fp[f];
      z0 = fmaf(v, cw[20+(f+1)*2+0], z0); z1 = fmaf(v, cw[20+(f+1)*2+1], z1);
    }
    tile[r][c] = (f32x2){z0, z1};
  }
  __syncthreads();
  #pragma unroll
  for (int k=0;k<16;++k){
    int i = tid + k*256;
    int r = i >> 6, c = i & 63;                     // r = node off, c = slice off
    zT[(size_t)(n0 + r)*NSL + s0 + c] = tile[c][r];
  }
}

// ---------------- generic tiled transpose of f32x2 matrix [R][C] -> [C][R] ----
__global__ __launch_bounds__(256)
void k_tr(const f32x2* __restrict__ in, f32x2* __restrict__ out, int R, int C){
  __shared__ f32x2 tile[64][65];
  int tilesR = R >> 6;
  int br = blockIdx.x % tilesR, bc = blockIdx.x / tilesR;
  int r0 = br << 6, c0 = bc << 6;
  for (int i=threadIdx.x; i<4096; i+=256){
    int r = i>>6, c = i&63;
    tile[r][c] = in[(size_t)(r0+r)*C + c0+c];
  }
  __syncthreads();
  for (int i=threadIdx.x; i<4096; i+=256){
    int r = i>>6, c = i&63;
    out[(size_t)(c0+r)*R + r0+c] = tile[c][r];
  }
}

// ---------------- column-split dense agg: 6 passes of 64 float4 cols ----------
__global__ __launch_bounds__(64)
void k_aggc(const int* __restrict__ ptr, const int2* __restrict__ epack,
            const float4* __restrict__ zT, float4* __restrict__ aggT){
  int n  = blockIdx.x & (Nn-1);
  int cb = blockIdx.x >> 12;
  int col = cb*64 + threadIdx.x;              // float4 index in 384-wide row
  int p0 = ptr[n], p1 = ptr[n+1];
  f32x4 acc = {0.f,0.f,0.f,0.f};
  int i = p0;
  for (; i+1 < p1; i += 2){
    int2 e0 = epack[i], e1 = epack[i+1];
    float w0 = __int_as_float(e0.y), w1 = __int_as_float(e1.y);
    float4 z0 = zT[(size_t)e0.x*384 + col];
    float4 z1 = zT[(size_t)e1.x*384 + col];
    acc.x = fmaf(w0, z0.x, acc.x); acc.y = fmaf(w0, z0.y, acc.y);
    acc.z = fmaf(w0, z0.z, acc.z); acc.w = fmaf(w0, z0.w, acc.w);
    acc.x = fmaf(w1, z1.x, acc.x); acc.y = fmaf(w1, z1.y, acc.y);
    acc.z = fmaf(w1, z1.z, acc.z); acc.w = fmaf(w1, z1.w, acc.w);
  }
  if (i < p1){
    int2 e = epack[i];
    float w = __int_as_float(e.y);
    float4 z = zT[(size_t)e.x*384 + col];
    acc.x = fmaf(w, z.x, acc.x); acc.y = fmaf(w, z.y, acc.y);
    acc.z = fmaf(w, z.z, acc.z); acc.w = fmaf(w, z.w, acc.w);
  }
  aggT[(size_t)n*384 + col] = make_float4(acc.x, acc.y, acc.z, acc.w);
}

// ---------------- MFMA LSTM pointwise helper (round-15 proven) ----------------
#define POINTWISE(r)                                                            \
  c0[r] = fmaf(sigm_f(acc[0][r]), tanh_f(acc[4][r]), sigm_f(acc[2][r])*c0[r]);  \
  h0[r] = sigm_f(acc[6][r])*tanh_f(c0[r]);                                      \
  c1[r] = fmaf(sigm_f(acc[1][r]), tanh_f(acc[5][r]), sigm_f(acc[3][r])*c1[r]);  \
  h1[r] = sigm_f(acc[7][r])*tanh_f(c1[r]);

// ---------------- persistent history LSTM: weights in LDS, 1 tile/wave --------
__global__ __launch_bounds__(256,1)
void k_hist(const float* __restrict__ pm25, const float* __restrict__ feat,
            const f32x2* __restrict__ aggH,
            const float* __restrict__ cw, const float* __restrict__ cb,
            const uint4* __restrict__ wfrag,
            const float* __restrict__ fcw, const float* __restrict__ fcb,
            uint4* __restrict__ hfragO, uint4* __restrict__ cO,
            float* __restrict__ xn0){
  __shared__ __align__(16) uint4 wl[1024];          // 16 KB weight fragments
  __shared__ __align__(16) _Float16 hl[4][16][40];
  int tid = threadIdx.x;
  int lane = tid & 63, w = tid >> 6;
  for (int i = tid; i < 1024; i += 256) wl[i] = wfrag[i];
  int gw = blockIdx.x*4 + w;
  int r0 = gw*16;
  int b = r0 >> 12, n0 = r0 & (Nn-1);
  int l15 = lane & 15, g4 = lane >> 4;
  int nrow = n0 + l15;
  const float* pb = pm25 + (size_t)b*HISTC*Nn + nrow;
  const float* fb = feat + ((size_t)b*TTC*Nn + nrow)*9;

  float fw0 = fcw[l15], fw1 = fcw[l15+16];
  const f32x4 zacc = {0.f,0.f,0.f,0.f};

  uint4 ah = make_uint4(0,0,0,0);
  float c0[4]={0,0,0,0}, c1[4]={0,0,0,0};
  float h0[4], h1[4];
  __syncthreads();                                  // wl ready

  #pragma unroll 1
  for (int t=0; t<HISTC; ++t){
    int wofs = lane;
    asm volatile("" : "+v"(wofs));                  // opaque: prevent hoisting wl reads
    const float* fbt = fb + (size_t)t*Nn*9;
    float xv[9]; float a0 = 0.f, a1 = 0.f; float x0 = 0.f;
    if (g4 == 0){
      x0 = pb[(size_t)t*Nn];
      #pragma unroll
      for (int f=0;f<7;++f) xv[f] = fbt[f];
      a0 = x0*cw[0]; a1 = x0*cw[1];
      #pragma unroll
      for (int f=0;f<7;++f){ a0 += xv[f]*cw[(f+1)*2]; a1 += xv[f]*cw[(f+1)*2+1]; }
    } else if (g4 == 1){
      xv[7] = fbt[7]; xv[8] = fbt[8];
      a0 = cb[0] + xv[7]*cw[16] + xv[8]*cw[18];
      a1 = cb[1] + xv[7]*cw[17] + xv[8]*cw[19];
    } else if (g4 == 2){
      f32x2 ag = aggH[((size_t)(t*Bb + b))*Nn + nrow];
      a0 = ag.x; a1 = ag.y;
    }
    a0 += __shfl_xor(a0, 16); a0 += __shfl_xor(a0, 32);
    a1 += __shfl_xor(a1, 16); a1 += __shfl_xor(a1, 32);
    float xg0 = sigm_f(a0), xg1 = sigm_f(a1);

    uint4 ax;
    if (g4 == 0){
      ax.x = pk2(x0, xv[0]);     ax.y = pk2(xv[1], xv[2]);
      ax.z = pk2(xv[3], xv[4]);  ax.w = pk2(xv[5], xv[6]);
    } else if (g4 == 1){
      ax.x = pk2(xv[7], xv[8]);  ax.y = pk2(xg0, xg1);
      ax.z = pk2(1.f, 0.f);      ax.w = 0u;
    } else {
      ax = make_uint4(0,0,0,0);
    }

    f32x4 acc[8];
    #pragma unroll
    for (int ct=0; ct<8; ++ct){
      uint4 b0 = wl[wofs + ct*64];
      uint4 b1 = wl[wofs + 512 + ct*64];
      acc[ct] = mfma16(ax, b0, zacc);
      acc[ct] = mfma16(ah, b1, acc[ct]);
    }

    POINTWISE(0) POINTWISE(1) POINTWISE(2) POINTWISE(3)

    #pragma unroll
    for (int r=0;r<4;++r){
      hl[w][g4*4+r][l15]    = (_Float16)h0[r];
      hl[w][g4*4+r][l15+16] = (_Float16)h1[r];
    }
    asm volatile("s_waitcnt lgkmcnt(0)" ::: "memory");
    ah = *(const uint4*)&hl[w][l15][g4*8];
  }

  hfragO[(size_t)gw*64 + lane] = ah;
  {
    uint4 cp;
    cp.x = pk2(c0[0], c0[1]); cp.y = pk2(c0[2], c0[3]);
    cp.z = pk2(c1[0], c1[1]); cp.w = pk2(c1[2], c1[3]);
    cO[(size_t)gw*64 + lane] = cp;
  }
  #pragma unroll
  for (int r=0;r<4;++r){
    float p = fmaf(h0[r], fw0, h1[r]*fw1);
    p += __shfl_xor(p, 1, 16); p += __shfl_xor(p, 2, 16);
    p += __shfl_xor(p, 4, 16); p += __shfl_xor(p, 8, 16);
    if (l15 == 0) xn0[r0 + g4*4 + r] = p + fcb[0];
  }
}

// ---------------- pred step: in-kernel xn gather + dense zf agg + MFMA cell ----
// xn ping-pong: reads xnI (prev step, all rows), writes xnO
__global__ __launch_bounds__(256,1)
void k_pred_cell(const float* __restrict__ feat,
                 const float* __restrict__ xnI, float* __restrict__ xnO,
                 const f32x2* __restrict__ aggzf,     // pre-offset by (512+tp*32)*Nn
                 const int* __restrict__ ptr, const int2* __restrict__ epack,
                 const float* __restrict__ cw, const float* __restrict__ cb,
                 const uint4* __restrict__ wfrag,
                 const float* __restrict__ fcw, const float* __restrict__ fcb,
                 uint4* __restrict__ hfrag, uint4* __restrict__ cS,
                 float* __restrict__ out, int t){
  __shared__ __align__(16) uint4 wl[1024];
  __shared__ __align__(16) _Float16 hl[4][16][40];
  int tid = threadIdx.x;
  int lane = tid & 63, w = tid >> 6;
  for (int i = tid; i < 1024; i += 256) wl[i] = wfrag[i];
  int gw = blockIdx.x*4 + w;
  int r0 = gw*16;
  int b = r0 >> 12, n0 = r0 & (Nn-1);
  int l15 = lane & 15, g4 = lane >> 4;
  int nrow = n0 + l15;

  float fw0 = fcw[l15], fw1 = fcw[l15+16];

  uint4 ah = hfrag[(size_t)gw*64 + lane];
  float c0[4], c1[4];
  {
    uint4 cv = cS[(size_t)gw*64 + lane];
    unpk2(cv.x, c0[0], c0[1]); unpk2(cv.y, c0[2], c0[3]);
    unpk2(cv.z, c1[0], c1[1]); unpk2(cv.w, c1[2], c1[3]);
  }
  float h0[4], h1[4];
  const f32x4 zacc = {0.f,0.f,0.f,0.f};

  const float* fbt = feat + ((size_t)(b*TTC + t)*Nn + nrow)*9;
  const float* xb = xnI + (size_t)b*Nn;
  float xv[9]; float a0 = 0.f, a1 = 0.f; float x0 = 0.f;
  if (g4 == 0){
    x0 = xb[nrow];
    #pragma unroll
    for (int f=0;f<7;++f) xv[f] = fbt[f];
    a0 = x0*cw[0]; a1 = x0*cw[1];
    #pragma unroll
    for (int f=0;f<7;++f){ a0 += xv[f]*cw[(f+1)*2]; a1 += xv[f]*cw[(f+1)*2+1]; }
  } else if (g4 == 1){
    xv[7] = fbt[7]; xv[8] = fbt[8];
    a0 = cb[0] + xv[7]*cw[16] + xv[8]*cw[18];
    a1 = cb[1] + xv[7]*cw[17] + xv[8]*cw[19];
  } else if (g4 == 2){
    f32x2 azf = aggzf[(size_t)b*Nn + nrow];
    a0 = azf.x; a1 = azf.y;
  }
  // in-wave xn sparse gather: 4 lanes (g4) split row nrow's CSR range
  {
    int p0 = ptr[nrow], p1 = ptr[nrow+1];
    float pax = 0.f;
    for (int i = p0 + g4; i < p1; i += 4){
      int2 e = epack[i];
      pax = fmaf(__int_as_float(e.y), xb[e.x], pax);
    }
    a0 = fmaf(pax, cw[20], a0);
    a1 = fmaf(pax, cw[21], a1);
  }
  a0 += __shfl_xor(a0, 16); a0 += __shfl_xor(a0, 32);
  a1 += __shfl_xor(a1, 16); a1 += __shfl_xor(a1, 32);
  float xg0 = sigm_f(a0), xg1 = sigm_f(a1);

  uint4 ax;
  if (g4 == 0){
    ax.x = pk2(x0, xv[0]);     ax.y = pk2(xv[1], xv[2]);
    ax.z = pk2(xv[3], xv[4]);  ax.w = pk2(xv[5], xv[6]);
  } else if (g4 == 1){
    ax.x = pk2(xv[7], xv[8]);  ax.y = pk2(xg0, xg1);
    ax.z = pk2(1.f, 0.f);      ax.w = 0u;
  } else {
    ax = make_uint4(0,0,0,0);
  }

  __syncthreads();                                  // wl ready
  f32x4 acc[8];
  #pragma unroll
  for (int ct=0; ct<8; ++ct){
    uint4 b0 = wl[lane + ct*64];
    uint4 b1 = wl[lane + 512 + ct*64];
    acc[ct] = mfma16(ax, b0, zacc);
    acc[ct] = mfma16(ah, b1, acc[ct]);
  }

  POINTWISE(0) POINTWISE(1) POINTWISE(2) POINTWISE(3)

  #pragma unroll
  for (int r=0;r<4;++r){
    hl[w][g4*4+r][l15]    = (_Float16)h0[r];
    hl[w][g4*4+r][l15+16] = (_Float16)h1[r];
  }
  asm volatile("s_waitcnt lgkmcnt(0)" ::: "memory");
  ah = *(const uint4*)&hl[w][l15][g4*8];

  hfrag[(size_t)gw*64 + lane] = ah;
  {
    uint4 cp;
    cp.x = pk2(c0[0], c0[1]); cp.y = pk2(c0[2], c0[3]);
    cp.z = pk2(c1[0], c1[1]); cp.w = pk2(c1[2], c1[3]);
    cS[(size_t)gw*64 + lane] = cp;
  }
  #pragma unroll
  for (int r=0;r<4;++r){
    float p = fmaf(h0[r], fw0, h1[r]*fw1);
    p += __shfl_xor(p, 1, 16); p += __shfl_xor(p, 2, 16);
    p += __shfl_xor(p, 4, 16); p += __shfl_xor(p, 8, 16);
    if (l15 == 0){
      float rr = p + fcb[0];
      int nr = n0 + g4*4 + r;
      xnO[r0 + g4*4 + r] = rr;
      out[(size_t)b*PREDC*Nn + nr] = rr;      // out pre-offset by tp*Nn
    }
  }
}

// ---------------- host ----------------
extern "C" void kernel_launch(void* const* d_in, const int* in_sizes, int n_in,
                              void* d_out, int out_size, void* d_ws, size_t ws_size,
                              hipStream_t stream){
  const float* pm25 = (const float*)d_in[0];
  const float* feat = (const float*)d_in[1];
  const int*   ei   = (const int*)d_in[2];
  const float* cw   = (const float*)d_in[3];
  const float* cb   = (const float*)d_in[4];
  const float* x2hw = (const float*)d_in[5];
  const float* x2hb = (const float*)d_in[6];
  const float* h2hw = (const float*)d_in[7];
  const float* h2hb = (const float*)d_in[8];
  const float* fcw  = (const float*)d_in[9];
  const float* fcb  = (const float*)d_in[10];
  float* out = (float*)d_out;

  char* wsp = (char*)d_ws;
  size_t off = 0;
  auto take = [&](size_t bytes)->char*{
    char* r = wsp + off; off += (bytes + 255) & ~(size_t)255; return r;
  };
  int*      deg   = (int*)      take(Nn*4);
  int*      cnt   = (int*)      take(Nn*4);
  int*      fillc = (int*)      take(Nn*4);
  int*      ptr   = (int*)      take((Nn+1)*4);
  float*    dis   = (float*)    take(Nn*4);
  int2*     epack = (int2*)     take(EC*8);
  _Float16* wfrag = (_Float16*) take(16*512*2);
  char*     bufA  =             take((size_t)NSL*Nn*8);   // aggT -> {hfrag,cbuf}
  char*     bufB  =             take((size_t)NSL*Nn*8);   // zT   -> aggAll
  float*    xn0   = (float*)    take((size_t)BN*4);
  float*    xn1   = (float*)    take((size_t)BN*4);

  uint4*  hfrag = (uint4*)bufA;                           // reuse after agg pipeline
  uint4*  cbuf  = (uint4*)(bufA + (size_t)8388608);       // f16-packed c state

  (void)hipMemsetAsync(deg, 0, Nn*4*3, stream);   // deg,cnt,fillc adjacent

  k_deg <<<EC/256, 256, 0, stream>>>(ei, deg, cnt);
  k_scan<<<1, 1024, 0, stream>>>(cnt, ptr);
  k_misc<<<9, 1024, 0, stream>>>(deg, dis, x2hw, h2hw, x2hb, h2hb, wfrag);
  k_fill<<<EC/256, 256, 0, stream>>>(ei, dis, ptr, fillc, epack);

  // dense agg pipeline: fused z+transpose -> dense agg -> transpose back
  k_zt<<<(NSL/64)*(Nn/64), 256, 0, stream>>>(pm25, feat, cw, (f32x2*)bufB);
  k_aggc<<<6*Nn, 64, 0, stream>>>(ptr, epack, (const float4*)bufB, (float4*)bufA);
  k_tr<<<(Nn/64)*(NSL/64), 256, 0, stream>>>((const f32x2*)bufA, (f32x2*)bufB, Nn, NSL);

  const f32x2* aggAll = (const f32x2*)bufB;     // [768][4096]

  k_hist<<<BN/64, 256, 0, stream>>>(pm25, feat, aggAll, cw, cb,
                                    (const uint4*)wfrag, fcw, fcb,
                                    hfrag, cbuf, xn0);

  for (int tp = 0; tp < PREDC; ++tp){
    int t = HISTC + tp;
    const float* xi = (tp & 1) ? xn1 : xn0;
    float*       xo = (tp & 1) ? xn0 : xn1;
    k_pred_cell<<<BN/64, 256, 0, stream>>>(feat, xi, xo,
                                           aggAll + (size_t)(512 + tp*Bb)*Nn,
                                           ptr, epack, cw, cb,
                                           (const uint4*)wfrag, fcw, fcb,
                                           hfrag, cbuf, out + (size_t)tp*Nn, t);
  }
}